// Round 1
// baseline (177.282 us; speedup 1.0000x reference)
//
#include <hip/hip_runtime.h>
#include <math.h>

// InteractionBlock: per-edge equivariant message passing + scatter-add.
// E = 160000, N = 10000, ATOMIC_DIM=EDGE_DIM=HIDDEN_DIM=16, L={0,1,2} -> 144 msg elems.
//
// Design (round 1):
//  - pass 1: per-thread activity flag (0 < dist < 6); ~43% of edges survive.
//            ballot + prefix-sum compaction into LDS (dead edges give exactly-0
//            messages since silu(0)=0).
//  - pass 2: 16 threads per active edge (thread = h index). W2 staged in LDS,
//            transposed to [k][l][h][c] with row stride 20 floats (80B) so the
//            c-contiguous reads are ds_read_b128, 16B-aligned, 2-way-bank-free.
//  - scatter: 9 global f32 atomicAdds per (edge, h) thread.
// All scalar factors folded: edge_z/sqrt(16) * inv_sqrt_c(1/4) * degree(1/16) = 1/256.

#define W2S 20  // LDS row stride in floats for the transposed W2 tile

__global__ __launch_bounds__(256, 2)
void interact_kernel(const float* __restrict__ xfeat,
                     const float* __restrict__ coords,
                     const int* __restrict__ eidx,
                     const float* __restrict__ W1g,
                     const float* __restrict__ W2g,
                     float* __restrict__ out,
                     int E, int ntiles)
{
  __shared__ float W2s[768 * W2S];           // 61440 B
  __shared__ float W1s[256];                 // [k][j]
  __shared__ float xss[16][16];              // per-edge src features
  __shared__ float hss[16][16];              // per-edge hidden vec
  __shared__ unsigned char clist[256];       // compacted tile-local edge ids
  __shared__ int wsum[4];                    // per-wave active counts

  const int tid = threadIdx.x;

  // stage W1 (flat [k*16+j]) and W2 transposed:
  // global idx t = k*768 + l*256 + c*16 + h  ->  LDS ((k*3+l)*16 + h)*W2S + c
  W1s[tid] = W1g[tid];
  for (int t = tid; t < 12288; t += 256) {
    int k = t / 768;
    int r = t - k * 768;
    int l = r >> 8;
    int rc = r & 255;
    int c = rc >> 4;
    int h = rc & 15;
    W2s[((k * 3 + l) * 16 + h) * W2S + c] = W2g[t];
  }
  __syncthreads();

  const int slot  = tid >> 4;   // which of 16 edges in a sub-group
  const int jlane = tid & 15;   // h index
  const int wid   = tid >> 6;
  const int lane  = tid & 63;

  for (int tile = blockIdx.x; tile < ntiles; tile += gridDim.x) {
    const int ebase = tile * 256;

    // ---- pass 1: activity + compaction ----
    int e = ebase + tid;
    bool act = false;
    if (e < E) {
      int s = eidx[e], d = eidx[E + e];
      float rx = coords[3*s]   - coords[3*d];
      float ry = coords[3*s+1] - coords[3*d+1];
      float rz = coords[3*s+2] - coords[3*d+2];
      float d2 = rx*rx + ry*ry + rz*rz;
      act = (d2 > 0.0f) && (d2 < 36.0f);   // 0 < dist < cutoff
    }
    unsigned long long bm = __ballot(act);
    int pfx = __popcll(bm & ((1ull << lane) - 1ull));
    if (lane == 0) wsum[wid] = __popcll(bm);
    __syncthreads();
    int base = 0;
    #pragma unroll
    for (int w = 0; w < 4; w++) base += (w < wid) ? wsum[w] : 0;
    const int total = wsum[0] + wsum[1] + wsum[2] + wsum[3];
    if (act) clist[base + pfx] = (unsigned char)tid;
    __syncthreads();

    // ---- pass 2: 16 threads per active edge ----
    for (int s0 = 0; s0 < total; s0 += 16) {
      const int ci = s0 + slot;
      const bool on = ci < total;
      int dst = 0;
      float Y[9];
      if (on) {
        const int ee  = ebase + (int)clist[ci];
        const int src = eidx[ee];
        dst = eidx[E + ee];
        float rx = coords[3*src]   - coords[3*dst];
        float ry = coords[3*src+1] - coords[3*dst+1];
        float rz = coords[3*src+2] - coords[3*dst+2];
        float dd  = sqrtf(rx*rx + ry*ry + rz*rz);
        float inv = 1.0f / dd;
        float x = rx*inv, y = ry*inv, z = rz*inv;
        // spherical harmonics with 1/sqrt(4pi) folded in
        const float A0 = 0.28209479177387814f;  // 1/sqrt(4pi)
        const float A1 = 0.48860251190291992f;  // sqrt(3)/sqrt(4pi)
        const float A2 = 1.09254843059207907f;  // sqrt(15)/sqrt(4pi)
        const float A3 = 0.63078313050504001f;  // sqrt(5)/sqrt(4pi)
        Y[0] = A0;
        Y[1] = A1*x;   Y[2] = A1*y;   Y[3] = A1*z;
        Y[4] = A2*x*z; Y[5] = A2*x*y;
        Y[6] = A3*(y*y - 0.5f*(x*x + z*z));
        Y[7] = A2*y*z;
        Y[8] = 0.5f*A2*(z*z - x*x);
        // bessel: eb[k] = 4*sqrt(1/3)*sin((k+1)*pi*d/6)/d, via sin recurrence
        float theta = 0.52359877559829887f * dd;  // pi/6 * d
        float s1 = __sinf(theta), c1 = __cosf(theta);
        float snm = 0.0f, sn = s1, bsum = 0.0f;
        #pragma unroll
        for (int k = 0; k < 16; k++) {
          bsum = fmaf(sn, W1s[k*16 + jlane], bsum);
          float sp = 2.0f*c1*sn - snm;
          snm = sn; sn = sp;
        }
        float p  = bsum * (2.30940107675850305f * inv) * 0.25f; // *4sqrt(1/3)/d /sqrt(16)
        float hv = 1.679177f * p / (1.0f + __expf(-p));         // gain * silu
        hss[slot][jlane] = hv;
        xss[slot][jlane] = xfeat[src*16 + jlane];
      }
      __syncthreads();
      if (on) {
        float acc[3][16];
        #pragma unroll
        for (int l = 0; l < 3; l++)
          #pragma unroll
          for (int c = 0; c < 16; c++) acc[l][c] = 0.0f;
        #pragma unroll
        for (int k = 0; k < 16; k++) {
          const float hk = hss[slot][k];
          #pragma unroll
          for (int l = 0; l < 3; l++) {
            const float* wr = &W2s[((k*3 + l)*16 + jlane) * W2S];
            #pragma unroll
            for (int c = 0; c < 16; c++)
              acc[l][c] = fmaf(hk, wr[c], acc[l][c]);
          }
        }
        float v0 = 0.f, v1 = 0.f, v2 = 0.f;
        #pragma unroll
        for (int c = 0; c < 16; c++) {
          const float xc = xss[slot][c];
          v0 = fmaf(xc, acc[0][c], v0);
          v1 = fmaf(xc, acc[1][c], v1);
          v2 = fmaf(xc, acc[2][c], v2);
        }
        const float sc = 0.00390625f;  // 1/256
        v0 *= sc; v1 *= sc; v2 *= sc;
        float* o = out + (size_t)dst * 144;
        atomicAdd(o + jlane, v0 * Y[0]);
        #pragma unroll
        for (int mm = 0; mm < 3; mm++)
          atomicAdd(o + 16 + jlane*3 + mm, v1 * Y[1 + mm]);
        #pragma unroll
        for (int mm = 0; mm < 5; mm++)
          atomicAdd(o + 64 + jlane*5 + mm, v2 * Y[4 + mm]);
      }
      __syncthreads();
    }
    __syncthreads();  // protect wsum/clist before next tile
  }
}

extern "C" void kernel_launch(void* const* d_in, const int* in_sizes, int n_in,
                              void* d_out, int out_size, void* d_ws, size_t ws_size,
                              hipStream_t stream) {
  const float* xfeat  = (const float*)d_in[0];
  const float* coords = (const float*)d_in[1];
  const int*   eidx   = (const int*)d_in[2];
  const float* W1     = (const float*)d_in[3];
  const float* W2     = (const float*)d_in[4];
  float* out = (float*)d_out;

  const int E = in_sizes[2] / 2;
  const int ntiles = (E + 255) / 256;

  hipMemsetAsync(d_out, 0, (size_t)out_size * sizeof(float), stream);

  int nblk = ntiles < 4096 ? ntiles : 4096;
  interact_kernel<<<nblk, 256, 0, stream>>>(xfeat, coords, eidx, W1, W2, out, E, ntiles);
}